// Round 11
// baseline (166.241 us; speedup 1.0000x reference)
//
#include <hip/hip_runtime.h>
#include <cstddef>
#include <cstdint>

#define BN_EPS 1e-5f

typedef __attribute__((ext_vector_type(8))) __bf16 bf16x8;
typedef __attribute__((ext_vector_type(4))) float f32x4;

__device__ inline unsigned short f2bf(float f) {
    unsigned u = __builtin_bit_cast(unsigned, f);
    unsigned r = (u + 0x7fff + ((u >> 16) & 1)) >> 16;
    return (unsigned short)r;
}
__device__ inline float bf2f(unsigned short u) {
    return __builtin_bit_cast(float, (unsigned)u << 16);
}

#define GLDS16(g, l)                                                        \
    __builtin_amdgcn_global_load_lds(                                       \
        (const __attribute__((address_space(1))) void*)(g),                 \
        (__attribute__((address_space(3))) void*)(l), 16, 0, 0)

// ===========================================================================
// Prep kernel v3: NCHW f32 -> NHWC bf16 transpose, vectorized.
//   read : float4 per lane (1KB/wave-instr), ushort4 LDS writes
//   write: uint2 per lane (4 channels packed)
// Values bit-identical to rounds 8-10 prep (same f2bf per element, same
// zero-pad + guards). Block = 64 hw x 256 c (4 sequential 64x64 tiles).
// ===========================================================================
template<int HW, int NT64>
__device__ inline void transpose_body(int rb, const float* __restrict__ in,
                                      unsigned short* __restrict__ out)
{
    __shared__ unsigned short tl[64][68];    // [channel][hw], +4 pad
    const int tid = threadIdx.x;
    const int b = rb / NT64, ht = rb - b * NT64;
    const int hw0 = ht * 64;
    const int cl = tid >> 2, fx = tid & 3;   // read map
    const int j  = tid >> 2, u  = tid & 3;   // write map
    #pragma unroll
    for (int ct = 0; ct < 4; ++ct) {
        const int c0 = ct * 64;
        const float* ib = in + ((size_t)b * 256 + c0 + cl) * HW + hw0;
        #pragma unroll
        for (int k = 0; k < 4; ++k) {
            const int h = fx * 4 + k * 16;
            float4 v;
            if (hw0 + h + 3 < HW) {
                v = *(const float4*)(ib + h);
            } else {
                v.x = (hw0 + h + 0 < HW) ? ib[h + 0] : 0.f;
                v.y = (hw0 + h + 1 < HW) ? ib[h + 1] : 0.f;
                v.z = (hw0 + h + 2 < HW) ? ib[h + 2] : 0.f;
                v.w = (hw0 + h + 3 < HW) ? ib[h + 3] : 0.f;
            }
            ushort4 s;
            s.x = f2bf(v.x); s.y = f2bf(v.y); s.z = f2bf(v.z); s.w = f2bf(v.w);
            *(ushort4*)&tl[cl][h] = s;
        }
        __syncthreads();
        if (hw0 + j < HW) {
            unsigned short* ob = out + ((size_t)b * HW + hw0 + j) * 256 + c0;
            #pragma unroll
            for (int k = 0; k < 4; ++k) {
                const int cb = (u + k * 4) * 4;      // channel base, step 16
                uint2 wv;
                wv.x = (unsigned)tl[cb + 0][j] | ((unsigned)tl[cb + 1][j] << 16);
                wv.y = (unsigned)tl[cb + 2][j] | ((unsigned)tl[cb + 3][j] << 16);
                *(uint2*)(ob + cb) = wv;
            }
        }
        __syncthreads();
    }
}

__global__ __launch_bounds__(256)
void prep_kernel(const float* __restrict__ srch, const float* __restrict__ kin,
                 const float* __restrict__ cs_w, const float* __restrict__ ck_w,
                 const float* __restrict__ h1_w, const float* __restrict__ h2_w,
                 unsigned short* __restrict__ s16, unsigned short* __restrict__ k16,
                 unsigned short* __restrict__ wTs, unsigned short* __restrict__ wTk,
                 unsigned short* __restrict__ h1w16, unsigned short* __restrict__ h2w16,
                 int GS, int GK)
{
    const int bid = blockIdx.x;
    if (bid < GS) {
        transpose_body<961, 16>(bid, srch, s16);
    } else if (bid < GS + GK) {
        transpose_body<49, 1>(bid - GS, kin, k16);
    } else {
        const int base = (bid - GS - GK) * 2048 + threadIdx.x * 8;
        #pragma unroll
        for (int u = 0; u < 8; ++u) {
            const int i = base + u;
            if (i < 589824) {
                const int ic = i & 255, t = i >> 8, oc = t & 255, khkw = t >> 8;
                wTs[i] = f2bf(cs_w[(size_t)((oc << 8) + ic) * 9 + khkw]);
            } else if (i < 1179648) {
                const int j = i - 589824;
                const int ic = j & 255, t = j >> 8, oc = t & 255, khkw = t >> 8;
                wTk[j] = f2bf(ck_w[(size_t)((oc << 8) + ic) * 9 + khkw]);
            } else if (i < 1245184) {
                const int j = i - 1179648;
                h1w16[j] = f2bf(h1_w[j]);
            } else if (i < 1249280) {
                const int j = i - 1245184;
                const int oc = j >> 8, ic = j & 255;
                h2w16[j] = (oc < 10) ? f2bf(h2_w[oc * 256 + ic]) : (unsigned short)0;
            }
        }
    }
}

// ===========================================================================
// Combined 3x3 MFMA conv + BN + ReLU for BOTH branches (rounds 6-10 proven,
// unchanged). NHWC bf16 output.
// ===========================================================================
struct ConvParams {
    const unsigned short* bsrc;
    const unsigned short* wT;
    const float *bg, *bb, *bm, *bv;
    unsigned short* out;          // NHWC bf16 [pos][256]
    int IH, IW, OW, PPB, N;
};

__global__ __launch_bounds__(256)
void conv3x3_kernel(ConvParams S, ConvParams K, int Gs)
{
    __shared__ __align__(16) unsigned short Alds[128 * 64];
    __shared__ __align__(16) unsigned short Blds[128 * 64];

    const int tid  = threadIdx.x;
    const int lane = tid & 63;
    const int wid  = tid >> 6;

    const int raw = blockIdx.x;
    ConvParams P;
    int tileid;
    if (raw < Gs) {
        P = S;
        const int q8 = Gs >> 3, r8 = Gs & 7;
        const int xcd = raw & 7, seq = raw >> 3;
        tileid = (xcd < r8 ? xcd * (q8 + 1) : r8 * (q8 + 1) + (xcd - r8) * q8) + seq;
    } else {
        P = K;
        tileid = raw - Gs;
    }
    const int pt  = tileid >> 1;
    const int oct = tileid & 1;
    const int oc0 = oct << 7;
    const int p0  = pt << 7;

    int aoff[4], brow[4], bgs8[4], ldsrow[4];
    #pragma unroll
    for (int i = 0; i < 4; ++i) {
        const int r  = i * 32 + wid * 8 + (lane >> 3);
        const int gs = (lane & 7) ^ (r & 7);
        aoff[i] = (oc0 + r) * 256 + gs * 8;
        int pg = p0 + r; if (pg > P.N - 1) pg = P.N - 1;
        const int bb_ = pg / P.PPB;
        const int p   = pg - bb_ * P.PPB;
        const int oh  = p / P.OW, ow = p - oh * P.OW;
        brow[i] = (bb_ * P.IH + oh) * P.IW + ow;
        bgs8[i] = gs * 8;
        ldsrow[i] = (i * 32 + wid * 8) * 64;
    }

    const int q_  = lane >> 4;
    const int lr  = lane & 15;
    const int wm0 = (wid >> 1) * 64;
    const int wn0 = (wid & 1) * 64;
    const int g0  = q_ ^ (lane & 7);
    const int g1  = (4 + q_) ^ (lane & 7);
    const unsigned short* Abase = &Alds[(wm0 + lr) * 64];
    const unsigned short* Bbase = &Blds[(wn0 + lr) * 64];

    f32x4 acc[4][4] = {};

    int kh = 0, kw = 0;
    for (int khkw = 0; khkw < 9; ++khkw) {
        const size_t wslice = (size_t)khkw << 16;
        const int tapadd = kh * P.IW + kw;
        for (int ics = 0; ics < 4; ++ics) {
            const int ic0 = ics * 64;
            __syncthreads();
            #pragma unroll
            for (int i = 0; i < 4; ++i) {
                GLDS16(P.wT + wslice + aoff[i] + ic0, &Alds[ldsrow[i]]);
                GLDS16(P.bsrc + (size_t)(brow[i] + tapadd) * 256 + ic0 + bgs8[i],
                       &Blds[ldsrow[i]]);
            }
            __syncthreads();

            bf16x8 bfr[4][2];
            #pragma unroll
            for (int n = 0; n < 4; ++n) {
                bfr[n][0] = *(const bf16x8*)(Bbase + n * 1024 + g0 * 8);
                bfr[n][1] = *(const bf16x8*)(Bbase + n * 1024 + g1 * 8);
            }
            #pragma unroll
            for (int m = 0; m < 4; ++m) {
                bf16x8 a0 = *(const bf16x8*)(Abase + m * 1024 + g0 * 8);
                bf16x8 a1 = *(const bf16x8*)(Abase + m * 1024 + g1 * 8);
                #pragma unroll
                for (int n = 0; n < 4; ++n) {
                    acc[m][n] = __builtin_amdgcn_mfma_f32_16x16x32_bf16(
                                    a0, bfr[n][0], acc[m][n], 0, 0, 0);
                    acc[m][n] = __builtin_amdgcn_mfma_f32_16x16x32_bf16(
                                    a1, bfr[n][1], acc[m][n], 0, 0, 0);
                }
            }
        }
        if (++kw == 3) { kw = 0; ++kh; }
    }

    #pragma unroll
    for (int m = 0; m < 4; ++m) {
        const int ocm = oc0 + wm0 + m * 16 + q_ * 4;
        float sc[4], sh[4];
        #pragma unroll
        for (int r = 0; r < 4; ++r) {
            sc[r] = P.bg[ocm + r] * rsqrtf(P.bv[ocm + r] + BN_EPS);
            sh[r] = P.bb[ocm + r] - P.bm[ocm + r] * sc[r];
        }
        #pragma unroll
        for (int n = 0; n < 4; ++n) {
            const int pg = p0 + wn0 + n * 16 + lr;
            if (pg < P.N) {
                unsigned e0 = f2bf(fmaxf(acc[m][n][0] * sc[0] + sh[0], 0.f));
                unsigned e1 = f2bf(fmaxf(acc[m][n][1] * sc[1] + sh[1], 0.f));
                unsigned e2 = f2bf(fmaxf(acc[m][n][2] * sc[2] + sh[2], 0.f));
                unsigned e3 = f2bf(fmaxf(acc[m][n][3] * sc[3] + sh[3], 0.f));
                uint2 v; v.x = e0 | (e1 << 16); v.y = e2 | (e3 << 16);
                *(uint2*)(P.out + (size_t)pg * 256 + ocm) = v;
            }
        }
    }
}

// ===========================================================================
// Fused xcorr + head (rounds 8-10 proven, unchanged)
// ===========================================================================
__global__ __launch_bounds__(256)
void fused_xcorr_head_kernel(const unsigned short* __restrict__ sfeat,
                             const unsigned short* __restrict__ kfeat,
                             const unsigned short* __restrict__ h1w16,
                             const unsigned short* __restrict__ h2w16,
                             const float* __restrict__ bn_g,
                             const float* __restrict__ bn_b,
                             const float* __restrict__ bn_m,
                             const float* __restrict__ bn_v,
                             const float* __restrict__ h2b,
                             float* __restrict__ out)
{
    __shared__ __align__(16) unsigned short Alds[16384];
    __shared__ __align__(16) unsigned short Xlds[64 * 264];

    const int tid  = threadIdx.x;
    const int lane = tid & 63;
    const int wid  = tid >> 6;
    const int bid  = blockIdx.x;
    const int b    = bid / 10;
    const int pt   = bid - b * 10;
    const int p0   = pt * 64;

    {
        const int c = tid;
        float kv[25];
        const unsigned short* kp = kfeat + (size_t)b * 25 * 256 + c;
        #pragma unroll
        for (int t = 0; t < 25; ++t) kv[t] = bf2f(kp[t * 256]);

        if (pt == 9) {
            #pragma unroll
            for (int j = 49; j < 64; ++j) Xlds[j * 264 + c] = 0;
        }

        const int oh0 = p0 / 25;
        for (int ohr = 0; ohr < 4; ++ohr) {
            const int oh = oh0 + ohr;
            const int jbase = oh * 25 - p0;
            if (oh <= 24 && jbase < 64) {
                float acc[25];
                #pragma unroll
                for (int z = 0; z < 25; ++z) acc[z] = 0.f;
                const unsigned short* sp =
                    sfeat + ((size_t)(b * 29 + oh)) * 29 * 256 + c;
                #pragma unroll
                for (int i = 0; i < 5; ++i)
                    #pragma unroll
                    for (int w2 = 0; w2 < 29; ++w2) {
                        const float sv = bf2f(sp[(i * 29 + w2) * 256]);
                        #pragma unroll
                        for (int t = 0; t < 5; ++t) {
                            const int ww = w2 - t;
                            if (ww >= 0 && ww <= 24)
                                acc[ww] += sv * kv[i * 5 + t];
                        }
                    }
                #pragma unroll
                for (int ow = 0; ow < 25; ++ow) {
                    const int j = jbase + ow;
                    if (j >= 0 && j < 64)
                        Xlds[j * 264 + c] = f2bf(acc[ow]);
                }
            }
        }
    }

    const int lrow = lane >> 3;
    int aoffs[8], aldsr[8];
    #pragma unroll
    for (int s = 0; s < 8; ++s) {
        const int rowb = s * 32 + wid * 8;
        const int row  = rowb + lrow;
        const int g    = (lane & 7) ^ (row & 7);
        aoffs[s] = row * 256 + g * 8;
        aldsr[s] = rowb * 64;
    }
    const int q_ = lane >> 4;
    const int lr = lane & 15;
    const int wm = wid >> 1;
    const int wn = wid & 1;
    const int g0 = q_ ^ (lane & 7);
    const int g1 = (4 + q_) ^ (lane & 7);
    const unsigned short* Abase = &Alds[(wm * 128 + lr) * 64];

    f32x4 acc1[8][2] = {};

    for (int ics = 0; ics < 4; ++ics) {
        const int ic0 = ics * 64;
        __syncthreads();
        #pragma unroll
        for (int s = 0; s < 8; ++s)
            GLDS16(h1w16 + aoffs[s] + ic0, &Alds[aldsr[s]]);
        __syncthreads();

        bf16x8 bfr[2][2];
        #pragma unroll
        for (int n = 0; n < 2; ++n) {
            const int rowp = wn * 32 + n * 16 + lr;
            bfr[n][0] = *(const bf16x8*)(Xlds + rowp * 264 + ic0 + q_ * 8);
            bfr[n][1] = *(const bf16x8*)(Xlds + rowp * 264 + ic0 + 32 + q_ * 8);
        }
        #pragma unroll
        for (int m = 0; m < 8; ++m) {
            bf16x8 a0 = *(const bf16x8*)(Abase + m * 1024 + g0 * 8);
            bf16x8 a1 = *(const bf16x8*)(Abase + m * 1024 + g1 * 8);
            #pragma unroll
            for (int n = 0; n < 2; ++n) {
                acc1[m][n] = __builtin_amdgcn_mfma_f32_16x16x32_bf16(
                                 a0, bfr[n][0], acc1[m][n], 0, 0, 0);
                acc1[m][n] = __builtin_amdgcn_mfma_f32_16x16x32_bf16(
                                 a1, bfr[n][1], acc1[m][n], 0, 0, 0);
            }
        }
    }

    __syncthreads();
    #pragma unroll
    for (int m = 0; m < 8; ++m) {
        const int ocm = wm * 128 + m * 16 + q_ * 4;
        float sc[4], sh[4];
        #pragma unroll
        for (int r = 0; r < 4; ++r) {
            sc[r] = bn_g[ocm + r] * rsqrtf(bn_v[ocm + r] + BN_EPS);
            sh[r] = bn_b[ocm + r] - bn_m[ocm + r] * sc[r];
        }
        #pragma unroll
        for (int n = 0; n < 2; ++n) {
            const int pl = wn * 32 + n * 16 + lr;
            unsigned e0 = f2bf(fmaxf(acc1[m][n][0] * sc[0] + sh[0], 0.f));
            unsigned e1 = f2bf(fmaxf(acc1[m][n][1] * sc[1] + sh[1], 0.f));
            unsigned e2 = f2bf(fmaxf(acc1[m][n][2] * sc[2] + sh[2], 0.f));
            unsigned e3 = f2bf(fmaxf(acc1[m][n][3] * sc[3] + sh[3], 0.f));
            uint2 v; v.x = e0 | (e1 << 16); v.y = e2 | (e3 << 16);
            *(uint2*)(Xlds + (size_t)pl * 264 + ocm) = v;
        }
    }
    __syncthreads();

    const int pl = wid * 16 + lr;
    const unsigned short* arow = h2w16 + lr * 256 + q_ * 8;
    const unsigned short* brow = Xlds + (size_t)pl * 264 + q_ * 8;

    f32x4 acc2 = {};
    #pragma unroll
    for (int ks = 0; ks < 8; ++ks) {
        bf16x8 a  = *(const bf16x8*)(arow + ks * 32);
        bf16x8 bb = *(const bf16x8*)(brow + ks * 32);
        acc2 = __builtin_amdgcn_mfma_f32_16x16x32_bf16(a, bb, acc2, 0, 0, 0);
    }

    const int plocal = p0 + pl;
    if (plocal < 625) {
        #pragma unroll
        for (int r = 0; r < 4; ++r) {
            const int oc = q_ * 4 + r;
            if (oc < 10)
                out[((size_t)(b * 10 + oc)) * 625 + plocal] = acc2[r] + h2b[oc];
        }
    }
}

// ===========================================================================
extern "C" void kernel_launch(void* const* d_in, const int* in_sizes, int n_in,
                              void* d_out, int out_size, void* d_ws, size_t ws_size,
                              hipStream_t stream)
{
    const float* kin  = (const float*)d_in[0];
    const float* srch = (const float*)d_in[1];
    const float* ck_w = (const float*)d_in[2];
    const float* ck_g = (const float*)d_in[3];
    const float* ck_b = (const float*)d_in[4];
    const float* ck_m = (const float*)d_in[5];
    const float* ck_v = (const float*)d_in[6];
    const float* cs_w = (const float*)d_in[7];
    const float* cs_g = (const float*)d_in[8];
    const float* cs_b = (const float*)d_in[9];
    const float* cs_m = (const float*)d_in[10];
    const float* cs_v = (const float*)d_in[11];
    const float* h1_w = (const float*)d_in[12];
    const float* h_g  = (const float*)d_in[13];
    const float* h_b  = (const float*)d_in[14];
    const float* h_m  = (const float*)d_in[15];
    const float* h_v  = (const float*)d_in[16];
    const float* h2_w = (const float*)d_in[17];
    const float* h2_b = (const float*)d_in[18];

    const int B = in_sizes[0] / (256 * 7 * 7);   // 64

    // ---- workspace layout (round-8, unchanged) ----
    uint8_t* w = (uint8_t*)d_ws;
    unsigned short* s16     = (unsigned short*)(w);             // B*31*31*256 bf16
    unsigned short* sfeat16 = (unsigned short*)(w + 31490048);  // B*841*256 bf16
    unsigned short* kf16    = (unsigned short*)(w + 59047936);  // B*25*256 bf16
    unsigned short* k16     = (unsigned short*)(w + 59867136);  // B*7*7*256 bf16
    unsigned short* wTk     = (unsigned short*)(w + 61472768);
    unsigned short* wTs     = (unsigned short*)(w + 62652416);
    unsigned short* h1w16   = (unsigned short*)(w + 63832064);
    unsigned short* h2w16   = (unsigned short*)(w + 63963136);

    const int Ns = B * 841;    // 53824
    const int Nk = B * 25;     // 1600
    const int Gs = 2 * ((Ns + 127) / 128);   // 842
    const int Gk = 2 * ((Nk + 127) / 128);   // 26
    const int GS = B * 16;     // 1024 search-transpose blocks
    const int GK = B * 1;      // 64 kernel-transpose blocks
    const int GW = 610;        // weight-conversion blocks

    dim3 blk(256, 1, 1);

    // 1) prep: vectorized transposes + weight conversions
    hipLaunchKernelGGL(prep_kernel, dim3(GS + GK + GW), blk, 0, stream,
                       srch, kin, cs_w, ck_w, h1_w, h2_w,
                       s16, k16, wTs, wTk, h1w16, h2w16, GS, GK);

    // 2) both 3x3 convs (2-phase 128^2 proven structure)
    ConvParams S{ s16, wTs, cs_g, cs_b, cs_m, cs_v, sfeat16, 31, 31, 29, 841, Ns };
    ConvParams K{ k16, wTk, ck_g, ck_b, ck_m, ck_v, kf16, 7, 7, 5, 25, Nk };
    hipLaunchKernelGGL(conv3x3_kernel, dim3(Gs + Gk), blk, 0, stream, S, K, Gs);

    // 3) fused xcorr + head -> d_out
    hipLaunchKernelGGL(fused_xcorr_head_kernel, dim3(B * 10), blk, 0, stream,
                       sfeat16, kf16, h1w16, h2w16,
                       h_g, h_b, h_m, h_v, h2_b, (float*)d_out);
}